// Round 3
// baseline (319.414 us; speedup 1.0000x reference)
//
#include <hip/hip_runtime.h>
#include <stdint.h>

// Pipeline: scores+keys+global-16bit-hist -> threshold scan -> compact -> sort ->
// decode -> rank-merge order -> NMS bitmask (+sparsity) -> sparse greedy scan.
//
// Workspace layout (bytes), total ~2.06 MB:
//   keys   [86016] u64 @ 0        (live: k_scores..k_compact)
//   sup    [3008x47]u64 @ 0       (live: k_iou..k_scan; overlays dead keys)
//   ghist  [3x65536]u32 @ 1131008 (memset 0 each launch)
//   cnt    [8]     u32 @ 1917440  (memset 0 each launch)
//   t16    [24+pad]    @ 1917472
//   comp   [3x4096]u64 @ 1917568
//   topk   [3000]  u64 @ 2015872
//   order  [3000]  u32 @ 2039872
//   kwinit [47]    u64 @ 2051872
//   nlabel [3000]  i32 @ 2052256
//   nbox   [3000x4]f32 @ 2064256
//   diag   [3008]  u64 @ 2112256
//   rowfut [3008]  u64 @ 2136320

#define N_ALL 3000
#define N_PAD 3008
#define N_WORDS 47

typedef unsigned long long u64;
typedef uint32_t u32;

__device__ __forceinline__ u32 f32_ord(float x) {
    u32 u = __float_as_uint(x);
    return (u & 0x80000000u) ? ~u : (u | 0x80000000u);
}
__device__ __forceinline__ float ord_f32(u32 o) {
    u32 u = (o & 0x80000000u) ? (o & 0x7FFFFFFFu) : ~o;
    return __uint_as_float(u);
}
__device__ __forceinline__ u64 shfl_u64(u64 v, int src) {
    int lo = __shfl((int)(u32)(v & 0xFFFFFFFFull), src);
    int hi = __shfl((int)(u32)(v >> 32), src);
    return ((u64)(u32)hi << 32) | (u32)(unsigned)lo;
}

// ---------------- K1: per-anchor max-logit + argmax label -> unique key + global hist
__global__ __launch_bounds__(256) void k_scores(
        const float* __restrict__ cls0, const float* __restrict__ cls1,
        const float* __restrict__ cls2, u64* __restrict__ keys,
        u32* __restrict__ ghist) {
    int g = blockIdx.x * blockDim.x + threadIdx.x;
    if (g >= 86016) return;
    const float* row; int local, lvl;
    if (g < 65536)      { lvl = 0; local = g;         row = cls0 + (size_t)local * 80; }
    else if (g < 81920) { lvl = 1; local = g - 65536; row = cls1 + (size_t)local * 80; }
    else                { lvl = 2; local = g - 81920; row = cls2 + (size_t)local * 80; }
    const float4* r4 = (const float4*)row;
    float m = -3.4e38f; int lab = 0;
#pragma unroll
    for (int q = 0; q < 20; q++) {
        float4 v = r4[q];
        if (v.x > m) { m = v.x; lab = 4*q;   }   // strict > keeps FIRST max (jax argmax)
        if (v.y > m) { m = v.y; lab = 4*q+1; }
        if (v.z > m) { m = v.z; lab = 4*q+2; }
        if (v.w > m) { m = v.w; lab = 4*q+3; }
    }
    // key: logit desc primary, anchor index asc on ties (inverted idx), label packed low
    u64 key = ((u64)f32_ord(m) << 32)
            | ((u64)(0x1FFFFu - (u32)local) << 7)
            | (u64)lab;
    keys[g] = key;
    atomicAdd(&ghist[lvl * 65536 + (u32)(key >> 48)], 1u);   // device-wide 16-bit hist
}

// ---------------- K2a: find 16-bit prefix of the 1000th-largest key per level
__global__ __launch_bounds__(1024) void k_thresh(
        const u32* __restrict__ ghist, u32* __restrict__ t16) {
    int lvl = blockIdx.x;
    const u32* h = ghist + lvl * 65536;
    __shared__ u32 sc[1024];
    __shared__ u32 ss[16];
    int tid = threadIdx.x;
    u32 s = 0;
    const uint4* h4 = (const uint4*)(h + tid * 64);
#pragma unroll
    for (int q = 0; q < 16; q++) { uint4 v = h4[q]; s += v.x + v.y + v.z + v.w; }
    sc[tid] = s;
    __syncthreads();
    if (tid < 16) { u32 t = 0; for (int i = 0; i < 64; i++) t += sc[tid * 64 + i]; ss[tid] = t; }
    __syncthreads();
    if (tid == 0) {
        u32 need = 1000u, cum = 0;
        int sp = 15;
        for (; sp > 0; sp--) { if (cum + ss[sp] >= need) break; cum += ss[sp]; }
        int ch = sp * 64 + 63;
        for (; ch > 0; ch--) { if (cum + sc[ch] >= need) break; cum += sc[ch]; }
        int b = ch * 64 + 63;
        for (; b > 0; b--) { if (cum + h[b] >= need) break; cum += h[b]; }
        t16[lvl] = (u32)b;   // bucket where top-down cumulative crosses 1000
    }
}

// ---------------- K2b: compact all keys with prefix >= T16 (~1035 per level)
__global__ __launch_bounds__(256) void k_compact(
        const u64* __restrict__ keys, const u32* __restrict__ t16,
        u64* __restrict__ comp, u32* __restrict__ cnt) {
    int g = blockIdx.x * blockDim.x + threadIdx.x;
    if (g >= 86016) return;
    int lvl = (g < 65536) ? 0 : (g < 81920 ? 1 : 2);
    u64 key = keys[g];
    if ((u32)(key >> 48) >= t16[lvl]) {
        u32 p = atomicAdd(&cnt[lvl], 1u);
        if (p < 4096u) comp[lvl * 4096 + p] = key;
    }
}

// ---------------- K2c: sort compacted list desc (bitonic 4096), emit top-1000
__global__ __launch_bounds__(1024) void k_final(
        const u64* __restrict__ comp, const u32* __restrict__ cnt,
        u64* __restrict__ topk) {
    int lvl = blockIdx.x;
    __shared__ u64 s[4096];
    int tid = threadIdx.x;
    int C = (int)cnt[lvl]; if (C > 4096) C = 4096;
#pragma unroll
    for (int e = 0; e < 4; e++) {
        int i = e * 1024 + tid;
        s[i] = (i < C) ? comp[lvl * 4096 + i] : 0ull;   // pad 0 sorts last (keys unique, nonzero)
    }
    __syncthreads();
    for (int k = 2; k <= 4096; k <<= 1) {
        for (int j = k >> 1; j > 0; j >>= 1) {
#pragma unroll
            for (int e = 0; e < 4; e++) {
                int i = e * 1024 + tid, ixj = i ^ j;
                if (ixj > i) {
                    u64 a = s[i], b = s[ixj];
                    bool up = ((i & k) == 0);
                    if (up ? (a < b) : (a > b)) { s[i] = b; s[ixj] = a; }
                }
            }
            __syncthreads();
        }
    }
    if (tid < 1000) topk[lvl * 1000 + tid] = s[tid];
}

// ---------------- K3: decode boxes, write bbox/score/label outputs + NMS inputs
__global__ __launch_bounds__(256) void k_decode(
        const u64* __restrict__ topk,
        const float* __restrict__ reg0, const float* __restrict__ reg1,
        const float* __restrict__ reg2, const float* __restrict__ scales,
        float* __restrict__ out, float* __restrict__ nbox,
        int* __restrict__ nlabel) {
    int r = blockIdx.x * blockDim.x + threadIdx.x;
    if (r >= N_ALL) return;
    int lvl = r / 1000;
    u64 key = topk[r];
    u32 low = (u32)key;
    int lab = (int)(low & 0x7Fu);
    int local = 0x1FFFF - (int)((low >> 7) & 0x1FFFFu);
    float logit = ord_f32((u32)(key >> 32));
    float score = 1.0f / (1.0f + expf(-logit));
    const float* regp = (lvl == 0 ? reg0 : (lvl == 1 ? reg1 : reg2));
    float4 rg = *(const float4*)(regp + (size_t)local * 4);
    float scale = scales[lvl];
    int wlog = 8 - lvl;                       // grid width 256/128/64
    int x = local & ((1 << wlog) - 1);
    int y = local >> wlog;
    float stridef = (float)(8 << lvl);
    float ax = ((float)x + 0.5f) * stridef;
    float ay = ((float)y + 0.5f) * stridef;
    float sx = 1.0f / (1.0f + expf(-rg.x));
    float sy = 1.0f / (1.0f + expf(-rg.y));
    float cx = ax + (sx * 3.0f - 1.5f);
    float cy = ay + (sy * 3.0f - 1.5f);
    float ww = expf(rg.z * scale);
    float hh = expf(rg.w * scale);
    float b0 = (cx - 0.5f * ww) * stridef;    // reference multiplies by stride AGAIN
    float b1 = (cy - 0.5f * hh) * stridef;
    float b2 = (cx + 0.5f * ww) * stridef;
    float b3 = (cy + 0.5f * hh) * stridef;
    const float inv = 1.0f / 2048.0f;         // exact pow2, == division by 2048
    out[r * 4 + 0] = fminf(fmaxf(b0 * inv, 0.0f), 1.0f);
    out[r * 4 + 1] = fminf(fmaxf(b1 * inv, 0.0f), 1.0f);
    out[r * 4 + 2] = fminf(fmaxf(b2 * inv, 0.0f), 1.0f);
    out[r * 4 + 3] = fminf(fmaxf(b3 * inv, 0.0f), 1.0f);
    out[12000 + r] = score;
    out[15000 + r] = (float)lab;
    ((float4*)nbox)[r] = make_float4(b0, b1, b2, b3);
    nlabel[r] = lab;
}

// ---------------- K4: global NMS order by rank-merge of the 3 sorted lists.
__device__ __forceinline__ int cnt_desc(const u64* __restrict__ list, u64 x, bool strict) {
    int lo = 0, hi = 1000;
    while (lo < hi) {
        int mid = (lo + hi) >> 1;
        u64 v = list[mid];
        bool in = strict ? (v > x) : (v >= x);
        if (in) lo = mid + 1; else hi = mid;
    }
    return lo;
}
__global__ __launch_bounds__(1024) void k_order(
        const u64* __restrict__ topk, u32* __restrict__ order, u64* __restrict__ kwinit) {
    __shared__ u64 lkw[N_WORDS];
    int tid = threadIdx.x;
    if (tid < N_WORDS) lkw[tid] = 0;
    __syncthreads();
#pragma unroll
    for (int e = 0; e < 3; e++) {
        int i = e * 1024 + tid;
        if (i < N_ALL) {
            u64 key = topk[i];
            int lvl = (i >= 2000) ? 2 : (i >= 1000 ? 1 : 0);
            int rank = i - lvl * 1000;
#pragma unroll
            for (int L2 = 0; L2 < 3; L2++)
                if (L2 != lvl) rank += cnt_desc(topk + L2 * 1000, key, L2 > lvl);
            order[rank] = (u32)i;
            float logit = ord_f32((u32)(key >> 32));
            float score = 1.0f / (1.0f + expf(-logit));
            if (score >= 0.05f) atomicOr(&lkw[rank >> 6], 1ull << (rank & 63));
        }
    }
    __syncthreads();
    if (tid < N_WORDS) kwinit[tid] = lkw[tid];
}

// ---------------- K5: suppression bitmask rows + sparsity summaries.
// f64 IoU WITH class offset (boxes reach 65536 > 8192 class spacing).
__global__ __launch_bounds__(256) void k_iou(
        const u32* __restrict__ order, const float* __restrict__ nbox,
        const int* __restrict__ nlabel, u64* __restrict__ sup,
        u64* __restrict__ diag, u64* __restrict__ rowfut) {
    int s = blockIdx.x;
    int tid = threadIdx.x;
    __shared__ u64 s_rf;
    if (tid == 0) s_rf = 0;
    __syncthreads();
    int tword = s >> 6;
    bool srow_ok = (s < N_ALL);
    double ix1 = 0, iy1 = 0, ix2 = 0, iy2 = 0, iarea = 0;
    if (srow_ok) {
        u32 ri = order[s];
        float4 b = ((const float4*)nbox)[ri];
        double c = (double)nlabel[ri] * 8192.0;
        ix1 = (double)b.x + c; iy1 = (double)b.y + c;
        ix2 = (double)b.z + c; iy2 = (double)b.w + c;
        iarea = (ix2 - ix1) * (iy2 - iy1);
    }
    for (int j = tid; j < N_PAD; j += 256) {
        bool sb = false;
        if (srow_ok && j < N_ALL && j > s) {
            u32 rj = order[j];
            float4 bj = ((const float4*)nbox)[rj];
            double cj = (double)nlabel[rj] * 8192.0;
            double jx1 = (double)bj.x + cj, jy1 = (double)bj.y + cj;
            double jx2 = (double)bj.z + cj, jy2 = (double)bj.w + cj;
            double xx1 = fmax(ix1, jx1), yy1 = fmax(iy1, jy1);
            double xx2 = fmin(ix2, jx2), yy2 = fmin(iy2, jy2);
            double w = fmax(1e-10, xx2 - xx1);
            double h = fmax(1e-10, yy2 - yy1);
            double inter = w * h;
            double jarea = (jx2 - jx1) * (jy2 - jy1);
            double iou = inter / (iarea + jarea - inter + 1e-14);
            sb = (iou > 0.6);
        }
        u64 bal = __ballot(sb);
        if ((j & 63) == 0) {
            int w = j >> 6;
            sup[(size_t)s * N_WORDS + w] = bal;
            if (w == tword) diag[s] = bal;
            if (w > tword && bal) atomicOr(&s_rf, 1ull << w);
        }
    }
    __syncthreads();
    if (tid == 0) rowfut[s] = s_rf;
}

// ---------------- K6: sparse sequential greedy scan, single wave.
__global__ __launch_bounds__(64) void k_scan(
        const u64* __restrict__ sup, const u64* __restrict__ diag,
        const u64* __restrict__ rowfut, const u64* __restrict__ kwinit,
        const u32* __restrict__ order, float* __restrict__ out_keep) {
    int lane = threadIdx.x;
    u64 kw = (lane < N_WORDS) ? kwinit[lane] : 0ull;   // lane holds keep-word `lane`
    u64 d  = diag[lane];                               // tile 0 prefetch
    u64 rf = rowfut[lane];
    for (int t = 0; t < N_WORDS; t++) {
        u64 dn = 0, rfn = 0;
        if (t < N_WORDS - 1) {                         // prefetch next tile
            dn  = diag[(t + 1) * 64 + lane];
            rfn = rowfut[(t + 1) * 64 + lane];
        }
        u64 km = shfl_u64(kw, t);                      // keep word of this tile (uniform)
        u64 nzd = __ballot(d != 0ull);                 // rows with in-tile suppression bits
        u64 todo = nzd;
        while (true) {                                 // uniform loop, usually 0-3 iters
            u64 c = todo & km;
            if (!c) break;
            int b = __ffsll((long long)c) - 1;         // lowest unprocessed kept row
            todo &= ~(1ull << b);
            u64 m = shfl_u64(d, b);                    // its in-tile mask (bits > b only)
            km &= ~m;
        }
        if (lane == t) kw = km;
        u64 appl = km & __ballot(rf != 0ull);          // kept rows with future bits
        while (appl) {                                 // usually 0 iters
            int b = __ffsll((long long)appl) - 1;
            appl &= appl - 1;
            u64 rfb = shfl_u64(rf, b);                 // which words that row touches
            u64 m2 = 0ull;
            if (lane < N_WORDS && ((rfb >> lane) & 1ull))
                m2 = sup[(size_t)(t * 64 + b) * N_WORDS + lane];  // coalesced row slice
            kw &= ~m2;                                 // rfb bits are all > t
        }
        d = dn; rf = rfn;
    }
    if (lane < N_WORDS) {
#pragma unroll 16
        for (int b = 0; b < 64; b++) {
            int j = lane * 64 + b;
            if (j < N_ALL) out_keep[order[j]] = ((kw >> b) & 1ull) ? 1.0f : 0.0f;
        }
    }
}

extern "C" void kernel_launch(void* const* d_in, const int* in_sizes, int n_in,
                              void* d_out, int out_size, void* d_ws, size_t ws_size,
                              hipStream_t stream) {
    const float* cls0   = (const float*)d_in[0];
    const float* reg0   = (const float*)d_in[1];
    const float* cls1   = (const float*)d_in[2];
    const float* reg1   = (const float*)d_in[3];
    const float* cls2   = (const float*)d_in[4];
    const float* reg2   = (const float*)d_in[5];
    const float* scales = (const float*)d_in[6];
    float* out = (float*)d_out;
    char* ws = (char*)d_ws;
    u64* keys   = (u64*)(ws + 0);           // dead after k_compact
    u64* sup    = (u64*)(ws + 0);           // written by k_iou (after keys die)
    u32* ghist  = (u32*)(ws + 1131008);
    u32* cnt    = (u32*)(ws + 1917440);
    u32* t16    = (u32*)(ws + 1917472);
    u64* comp   = (u64*)(ws + 1917568);
    u64* topk   = (u64*)(ws + 2015872);
    u32* order  = (u32*)(ws + 2039872);
    u64* kwinit = (u64*)(ws + 2051872);
    int* nlabel = (int*)(ws + 2052256);
    float* nbox = (float*)(ws + 2064256);
    u64* diag   = (u64*)(ws + 2112256);
    u64* rowfut = (u64*)(ws + 2136320);

    hipMemsetAsync(ws + 1131008, 0, 786432 + 32, stream);   // ghist + cnt
    k_scores<<<336, 256, 0, stream>>>(cls0, cls1, cls2, keys, ghist);
    k_thresh<<<3, 1024, 0, stream>>>(ghist, t16);
    k_compact<<<336, 256, 0, stream>>>(keys, t16, comp, cnt);
    k_final<<<3, 1024, 0, stream>>>(comp, cnt, topk);
    k_decode<<<12, 256, 0, stream>>>(topk, reg0, reg1, reg2, scales, out, nbox, nlabel);
    k_order<<<1, 1024, 0, stream>>>(topk, order, kwinit);
    k_iou<<<N_PAD, 256, 0, stream>>>(order, nbox, nlabel, sup, diag, rowfut);
    k_scan<<<1, 64, 0, stream>>>(sup, diag, rowfut, kwinit, order, out + 18000);
}

// Round 4
// 214.022 us; speedup vs baseline: 1.4924x; 1.4924x over previous
//
#include <hip/hip_runtime.h>
#include <stdint.h>

// Pipeline: coalesced scores -> sampled threshold -> wave-aggregated compact ->
// rank-by-counting top-1000 (+ exact fallback, never taken) -> decode ->
// rank-merge order -> divide-free NMS bitmask -> sparse greedy scan.
//
// Workspace (bytes), ~1.43 MB:
//   keys   [86016] u64 @ 0         (live: k_scores..k_fallback)
//   sup    [3008x47]u64 @ 0        (live: k_iou..k_scan; overlays dead keys)
//   t16    [4]  u32 @ 1131008
//   cnt    [8]  u32 @ 1131024
//   comp   [3x6144]u64 @ 1131072
//   topk   [3000]u64 @ 1278528
//   order  [3000]u32 @ 1302528
//   kwinit [47] u64 @ 1314560
//   nlabel [3000]i32 @ 1314944
//   nbox   [3000x4]f32 @ 1326976
//   diag   [3008]u64 @ 1374976
//   rowfut [3008]u64 @ 1399040

#define N_ALL 3000
#define N_PAD 3008
#define N_WORDS 47
#define CAP 6144

typedef unsigned long long u64;
typedef uint32_t u32;

__device__ __forceinline__ u32 f32_ord(float x) {
    u32 u = __float_as_uint(x);
    return (u & 0x80000000u) ? ~u : (u | 0x80000000u);
}
__device__ __forceinline__ float ord_f32(u32 o) {
    u32 u = (o & 0x80000000u) ? (o & 0x7FFFFFFFu) : ~o;
    return __uint_as_float(u);
}
__device__ __forceinline__ u64 shfl_u64(u64 v, int src) {
    int lo = __shfl((int)(u32)(v & 0xFFFFFFFFull), src);
    int hi = __shfl((int)(u32)(v >> 32), src);
    return ((u64)(u32)hi << 32) | (u32)(unsigned)lo;
}

// ---------------- K1: coalesced LDS-staged max-logit + argmax -> unique key
// 64 anchors/block; 4 threads/anchor; shuffle-combine with exact first-max tie-break.
__global__ __launch_bounds__(256) void k_scores(
        const float* __restrict__ cls0, const float* __restrict__ cls1,
        const float* __restrict__ cls2, u64* __restrict__ keys) {
    __shared__ __align__(16) float tile[64 * 80];   // 20 KB
    int b = blockIdx.x;
    int lvl, local0, off;
    const float* base;
    if (b < 1024)      { lvl = 0; local0 = b * 64;          base = cls0; off = 0; }
    else if (b < 1280) { lvl = 1; local0 = (b - 1024) * 64; base = cls1; off = 65536; }
    else               { lvl = 2; local0 = (b - 1280) * 64; base = cls2; off = 81920; }
    (void)lvl;
    const float4* src = (const float4*)(base + (size_t)local0 * 80);
    float4* dst = (float4*)tile;
    int tid = threadIdx.x;
#pragma unroll
    for (int k = 0; k < 5; k++) dst[tid + k * 256] = src[tid + k * 256];
    __syncthreads();
    int a = tid >> 2, s = tid & 3;
    const float4* row = (const float4*)(tile + a * 80 + s * 20);
    float m = -3.4e38f; int lab = 0;
#pragma unroll
    for (int q = 0; q < 5; q++) {
        float4 v = row[q];
        int j0 = s * 20 + q * 4;
        if (v.x > m) { m = v.x; lab = j0;     }   // strict > keeps FIRST max (jax argmax)
        if (v.y > m) { m = v.y; lab = j0 + 1; }
        if (v.z > m) { m = v.z; lab = j0 + 2; }
        if (v.w > m) { m = v.w; lab = j0 + 3; }
    }
    // combine the 4 segments of an anchor (lanes 4a..4a+3, same wave since 4|64)
    float om = __shfl_xor(m, 1); int ol = __shfl_xor(lab, 1);
    if (om > m || (om == m && ol < lab)) { m = om; lab = ol; }
    om = __shfl_xor(m, 2); ol = __shfl_xor(lab, 2);
    if (om > m || (om == m && ol < lab)) { m = om; lab = ol; }
    if (s == 0) {
        int local = local0 + a;
        keys[off + local] = ((u64)f32_ord(m) << 32)
                          | ((u64)(0x1FFFFu - (u32)local) << 7)
                          | (u64)lab;
    }
}

// ---------------- K2a: sampled 16-bit threshold per level (+ zero counters).
// 4096 strided samples; exact r-th-largest sample prefix via 2 byte-hist passes.
// lvl2 samples the whole level -> exact. Targets keep E[survivors]~2000 (lvl0/1).
__global__ __launch_bounds__(1024) void k_sample(
        const u64* __restrict__ keys, u32* __restrict__ t16, u32* __restrict__ cnt) {
    int lvl = blockIdx.x;
    int off    = (lvl == 0) ? 0 : (lvl == 1 ? 65536 : 81920);
    int stride = (lvl == 0) ? 16 : (lvl == 1 ? 4 : 1);
    u32 r      = (lvl == 0) ? 125u : (lvl == 1 ? 500u : 1000u);
    __shared__ u32 hist[256];
    __shared__ u32 s_b7, s_r2, s_t;
    int tid = threadIdx.x;
    if (lvl == 0 && tid < 8) cnt[tid] = 0;
    u32 p[4];
#pragma unroll
    for (int k = 0; k < 4; k++)
        p[k] = (u32)(keys[off + (tid + k * 1024) * stride] >> 48);
    if (tid < 256) hist[tid] = 0;
    __syncthreads();
#pragma unroll
    for (int k = 0; k < 4; k++) atomicAdd(&hist[p[k] >> 8], 1u);
    __syncthreads();
    if (tid == 0) {
        u32 cum = 0; int b = 255;
        for (; b > 0; b--) { if (cum + hist[b] >= r) break; cum += hist[b]; }
        s_b7 = (u32)b; s_r2 = r - cum;
    }
    __syncthreads();
    u32 b7 = s_b7, r2 = s_r2;
    if (tid < 256) hist[tid] = 0;
    __syncthreads();
#pragma unroll
    for (int k = 0; k < 4; k++)
        if ((p[k] >> 8) == b7) atomicAdd(&hist[p[k] & 255u], 1u);
    __syncthreads();
    if (tid == 0) {
        u32 cum = 0; int b = 255;
        for (; b > 0; b--) { if (cum + hist[b] >= r2) break; cum += hist[b]; }
        s_t = (b7 << 8) | (u32)b;
        t16[lvl] = s_t;
    }
}

// ---------------- K2b: compact keys with prefix >= T16 (wave-aggregated atomics)
__global__ __launch_bounds__(256) void k_compact(
        const u64* __restrict__ keys, const u32* __restrict__ t16,
        u64* __restrict__ comp, u32* __restrict__ cnt) {
    int g = blockIdx.x * blockDim.x + threadIdx.x;
    if (g >= 86016) return;
    int lvl = (g < 65536) ? 0 : (g < 81920 ? 1 : 2);   // wave-uniform (boundaries 64-aligned)
    u64 key = keys[g];
    bool pred = ((u32)(key >> 48) >= t16[lvl]);
    u64 mask = __ballot(pred);
    if (mask) {
        int leader = __ffsll((long long)mask) - 1;
        int lane = threadIdx.x & 63;
        u32 base = 0;
        if (lane == leader) base = atomicAdd(&cnt[lvl], (u32)__popcll(mask));
        base = (u32)__shfl((int)base, leader);
        u32 myoff = (u32)__popcll(mask & ((1ull << lane) - 1ull));
        if (pred) { u32 pp = base + myoff; if (pp < CAP) comp[lvl * CAP + pp] = key; }
    }
}

// ---------------- K2c: rank-by-counting -> sorted top-1000 per level.
// 12 blocks/level; LDS-broadcast inner loop; unique keys -> unique ranks.
__global__ __launch_bounds__(256) void k_rank(
        const u64* __restrict__ comp, const u32* __restrict__ cnt,
        u64* __restrict__ topk) {
    int lvl = blockIdx.x / 12, sub = blockIdx.x % 12;
    u32 C = cnt[lvl];
    if (C < 1000u || C > (u32)CAP) return;   // k_fallback handles (never in practice)
    __shared__ u64 buf[CAP];                 // 48 KB
    int tid = threadIdx.x;
    for (int i = tid; i < (int)C; i += 256) buf[i] = comp[lvl * CAP + i];
    __syncthreads();
    for (int i = sub * 256 + tid; i < (int)C; i += 3072) {
        u64 x = buf[i];
        int rank = 0;
#pragma unroll 4
        for (int j = 0; j < (int)C; j++) rank += (buf[j] > x) ? 1 : 0;
        if (rank < 1000) topk[lvl * 1000 + rank] = x;
    }
}

// ---------------- K2d: exact fallback (runs only if sampling bound violated)
__global__ __launch_bounds__(1024) void k_fallback(
        const u64* __restrict__ keys, const u32* __restrict__ cnt,
        u64* __restrict__ topk) {
    int lvl = blockIdx.x;
    u32 C = cnt[lvl];
    if (C >= 1000u && C <= (u32)CAP) return;   // normal path succeeded
    int M = (lvl == 0) ? 65536 : (lvl == 1 ? 16384 : 4096);
    const u64* k = keys + ((lvl == 0) ? 0 : (lvl == 1 ? 65536 : 81920));
    __shared__ u32 hist[256];
    __shared__ u64 s_pref;
    __shared__ u32 s_kk, s_c;
    __shared__ u64 buf[1024];
    int tid = threadIdx.x;
    if (tid == 0) { s_pref = 0; s_kk = 1000u; s_c = 0; }
    for (int d = 7; d >= 0; d--) {
        if (tid < 256) hist[tid] = 0;
        __syncthreads();
        u64 pref = s_pref;
        for (int i = tid; i < M; i += 1024) {
            u64 key = k[i];
            if (d == 7 || (key >> ((d + 1) * 8)) == pref)
                atomicAdd(&hist[(u32)(key >> (d * 8)) & 255u], 1u);
        }
        __syncthreads();
        if (tid == 0) {
            u32 kk = s_kk, cum = 0;
            for (int b = 255; b >= 0; b--) {
                u32 h = hist[b];
                if (cum + h >= kk) { s_pref = (pref << 8) | (u32)b; s_kk = kk - cum; break; }
                cum += h;
            }
        }
        __syncthreads();
    }
    u64 T = s_pref;                             // exact 1000th-largest key
    for (int i = tid; i < M; i += 1024) {
        u64 key = k[i];
        if (key >= T) { u32 p = atomicAdd(&s_c, 1u); if (p < 1024u) buf[p] = key; }
    }
    __syncthreads();
    if (tid < 1000) {
        u64 x = buf[tid]; int rank = 0;
        for (int j = 0; j < 1000; j++) rank += (buf[j] > x) ? 1 : 0;
        topk[lvl * 1000 + rank] = x;
    }
}

// ---------------- K3: decode boxes, write bbox/score/label outputs + NMS inputs
__global__ __launch_bounds__(256) void k_decode(
        const u64* __restrict__ topk,
        const float* __restrict__ reg0, const float* __restrict__ reg1,
        const float* __restrict__ reg2, const float* __restrict__ scales,
        float* __restrict__ out, float* __restrict__ nbox,
        int* __restrict__ nlabel) {
    int r = blockIdx.x * blockDim.x + threadIdx.x;
    if (r >= N_ALL) return;
    int lvl = r / 1000;
    u64 key = topk[r];
    u32 low = (u32)key;
    int lab = (int)(low & 0x7Fu);
    int local = 0x1FFFF - (int)((low >> 7) & 0x1FFFFu);
    float logit = ord_f32((u32)(key >> 32));
    float score = 1.0f / (1.0f + expf(-logit));
    const float* regp = (lvl == 0 ? reg0 : (lvl == 1 ? reg1 : reg2));
    float4 rg = *(const float4*)(regp + (size_t)local * 4);
    float scale = scales[lvl];
    int wlog = 8 - lvl;                       // grid width 256/128/64
    int x = local & ((1 << wlog) - 1);
    int y = local >> wlog;
    float stridef = (float)(8 << lvl);
    float ax = ((float)x + 0.5f) * stridef;
    float ay = ((float)y + 0.5f) * stridef;
    float sx = 1.0f / (1.0f + expf(-rg.x));
    float sy = 1.0f / (1.0f + expf(-rg.y));
    float cx = ax + (sx * 3.0f - 1.5f);
    float cy = ay + (sy * 3.0f - 1.5f);
    float ww = expf(rg.z * scale);
    float hh = expf(rg.w * scale);
    float b0 = (cx - 0.5f * ww) * stridef;    // reference multiplies by stride AGAIN
    float b1 = (cy - 0.5f * hh) * stridef;
    float b2 = (cx + 0.5f * ww) * stridef;
    float b3 = (cy + 0.5f * hh) * stridef;
    const float inv = 1.0f / 2048.0f;         // exact pow2, == division by 2048
    out[r * 4 + 0] = fminf(fmaxf(b0 * inv, 0.0f), 1.0f);
    out[r * 4 + 1] = fminf(fmaxf(b1 * inv, 0.0f), 1.0f);
    out[r * 4 + 2] = fminf(fmaxf(b2 * inv, 0.0f), 1.0f);
    out[r * 4 + 3] = fminf(fmaxf(b3 * inv, 0.0f), 1.0f);
    out[12000 + r] = score;
    out[15000 + r] = (float)lab;
    ((float4*)nbox)[r] = make_float4(b0, b1, b2, b3);
    nlabel[r] = lab;
}

// ---------------- K4: global NMS order by rank-merge of the 3 sorted lists.
__device__ __forceinline__ int cnt_desc(const u64* __restrict__ list, u64 x, bool strict) {
    int lo = 0, hi = 1000;
    while (lo < hi) {
        int mid = (lo + hi) >> 1;
        u64 v = list[mid];
        bool in = strict ? (v > x) : (v >= x);
        if (in) lo = mid + 1; else hi = mid;
    }
    return lo;
}
__global__ __launch_bounds__(1024) void k_order(
        const u64* __restrict__ topk, u32* __restrict__ order, u64* __restrict__ kwinit) {
    __shared__ u64 lkw[N_WORDS];
    int tid = threadIdx.x;
    if (tid < N_WORDS) lkw[tid] = 0;
    __syncthreads();
#pragma unroll
    for (int e = 0; e < 3; e++) {
        int i = e * 1024 + tid;
        if (i < N_ALL) {
            u64 key = topk[i];
            int lvl = (i >= 2000) ? 2 : (i >= 1000 ? 1 : 0);
            int rank = i - lvl * 1000;
#pragma unroll
            for (int L2 = 0; L2 < 3; L2++)
                if (L2 != lvl) rank += cnt_desc(topk + L2 * 1000, key, L2 > lvl);
            order[rank] = (u32)i;
            float logit = ord_f32((u32)(key >> 32));
            float score = 1.0f / (1.0f + expf(-logit));
            if (score >= 0.05f) atomicOr(&lkw[rank >> 6], 1ull << (rank & 63));
        }
    }
    __syncthreads();
    if (tid < N_WORDS) kwinit[tid] = lkw[tid];
}

// ---------------- K5: suppression bitmask rows + sparsity summaries.
// Divide-free: iou > 0.6  <=>  inter > 0.6*union (union+eps > 0).
// f64 WITH class offset (boxes reach 65536 > 8192 class spacing).
__global__ __launch_bounds__(256) void k_iou(
        const u32* __restrict__ order, const float* __restrict__ nbox,
        const int* __restrict__ nlabel, u64* __restrict__ sup,
        u64* __restrict__ diag, u64* __restrict__ rowfut) {
    int s = blockIdx.x;
    int tid = threadIdx.x;
    __shared__ u64 s_rf;
    if (tid == 0) s_rf = 0;
    __syncthreads();
    int tword = s >> 6;
    bool srow_ok = (s < N_ALL);
    double ix1 = 0, iy1 = 0, ix2 = 0, iy2 = 0, iarea = 0;
    if (srow_ok) {
        u32 ri = order[s];
        float4 b = ((const float4*)nbox)[ri];
        double c = (double)nlabel[ri] * 8192.0;
        ix1 = (double)b.x + c; iy1 = (double)b.y + c;
        ix2 = (double)b.z + c; iy2 = (double)b.w + c;
        iarea = (ix2 - ix1) * (iy2 - iy1);
    }
    for (int j = tid; j < N_PAD; j += 256) {
        bool sb = false;
        if (srow_ok && j < N_ALL && j > s) {
            u32 rj = order[j];
            float4 bj = ((const float4*)nbox)[rj];
            double cj = (double)nlabel[rj] * 8192.0;
            double jx1 = (double)bj.x + cj, jy1 = (double)bj.y + cj;
            double jx2 = (double)bj.z + cj, jy2 = (double)bj.w + cj;
            double xx1 = fmax(ix1, jx1), yy1 = fmax(iy1, jy1);
            double xx2 = fmin(ix2, jx2), yy2 = fmin(iy2, jy2);
            double w = fmax(1e-10, xx2 - xx1);
            double h = fmax(1e-10, yy2 - yy1);
            double inter = w * h;
            double jarea = (jx2 - jx1) * (jy2 - jy1);
            double uni = iarea + jarea - inter + 1e-14;
            sb = inter > 0.6 * uni;
        }
        u64 bal = __ballot(sb);
        if ((j & 63) == 0) {
            int w = j >> 6;
            sup[(size_t)s * N_WORDS + w] = bal;
            if (w == tword) diag[s] = bal;
            if (w > tword && bal) atomicOr(&s_rf, 1ull << w);
        }
    }
    __syncthreads();
    if (tid == 0) rowfut[s] = s_rf;
}

// ---------------- K6: sparse sequential greedy scan, single wave.
__global__ __launch_bounds__(64) void k_scan(
        const u64* __restrict__ sup, const u64* __restrict__ diag,
        const u64* __restrict__ rowfut, const u64* __restrict__ kwinit,
        const u32* __restrict__ order, float* __restrict__ out_keep) {
    int lane = threadIdx.x;
    u64 kw = (lane < N_WORDS) ? kwinit[lane] : 0ull;   // lane holds keep-word `lane`
    u64 d  = diag[lane];                               // tile 0 prefetch
    u64 rf = rowfut[lane];
    for (int t = 0; t < N_WORDS; t++) {
        u64 dn = 0, rfn = 0;
        if (t < N_WORDS - 1) {                         // prefetch next tile
            dn  = diag[(t + 1) * 64 + lane];
            rfn = rowfut[(t + 1) * 64 + lane];
        }
        u64 km = shfl_u64(kw, t);                      // keep word of this tile (uniform)
        u64 nzd = __ballot(d != 0ull);                 // rows with in-tile suppression bits
        u64 todo = nzd;
        while (true) {                                 // uniform loop, usually 0-3 iters
            u64 c = todo & km;
            if (!c) break;
            int b = __ffsll((long long)c) - 1;         // lowest unprocessed kept row
            todo &= ~(1ull << b);
            u64 m = shfl_u64(d, b);                    // its in-tile mask (bits > b only)
            km &= ~m;
        }
        if (lane == t) kw = km;
        u64 appl = km & __ballot(rf != 0ull);          // kept rows with future bits
        while (appl) {                                 // usually 0 iters
            int b = __ffsll((long long)appl) - 1;
            appl &= appl - 1;
            u64 rfb = shfl_u64(rf, b);                 // which words that row touches
            u64 m2 = 0ull;
            if (lane < N_WORDS && ((rfb >> lane) & 1ull))
                m2 = sup[(size_t)(t * 64 + b) * N_WORDS + lane];  // coalesced row slice
            kw &= ~m2;                                 // rfb bits are all > t
        }
        d = dn; rf = rfn;
    }
    if (lane < N_WORDS) {
#pragma unroll 16
        for (int b = 0; b < 64; b++) {
            int j = lane * 64 + b;
            if (j < N_ALL) out_keep[order[j]] = ((kw >> b) & 1ull) ? 1.0f : 0.0f;
        }
    }
}

extern "C" void kernel_launch(void* const* d_in, const int* in_sizes, int n_in,
                              void* d_out, int out_size, void* d_ws, size_t ws_size,
                              hipStream_t stream) {
    const float* cls0   = (const float*)d_in[0];
    const float* reg0   = (const float*)d_in[1];
    const float* cls1   = (const float*)d_in[2];
    const float* reg1   = (const float*)d_in[3];
    const float* cls2   = (const float*)d_in[4];
    const float* reg2   = (const float*)d_in[5];
    const float* scales = (const float*)d_in[6];
    float* out = (float*)d_out;
    char* ws = (char*)d_ws;
    u64* keys   = (u64*)(ws + 0);           // dead after k_fallback
    u64* sup    = (u64*)(ws + 0);           // written by k_iou (after keys die)
    u32* t16    = (u32*)(ws + 1131008);
    u32* cnt    = (u32*)(ws + 1131024);
    u64* comp   = (u64*)(ws + 1131072);
    u64* topk   = (u64*)(ws + 1278528);
    u32* order  = (u32*)(ws + 1302528);
    u64* kwinit = (u64*)(ws + 1314560);
    int* nlabel = (int*)(ws + 1314944);
    float* nbox = (float*)(ws + 1326976);
    u64* diag   = (u64*)(ws + 1374976);
    u64* rowfut = (u64*)(ws + 1399040);

    k_scores<<<1344, 256, 0, stream>>>(cls0, cls1, cls2, keys);
    k_sample<<<3, 1024, 0, stream>>>(keys, t16, cnt);
    k_compact<<<336, 256, 0, stream>>>(keys, t16, comp, cnt);
    k_rank<<<36, 256, 0, stream>>>(comp, cnt, topk);
    k_fallback<<<3, 1024, 0, stream>>>(keys, cnt, topk);
    k_decode<<<12, 256, 0, stream>>>(topk, reg0, reg1, reg2, scales, out, nbox, nlabel);
    k_order<<<1, 1024, 0, stream>>>(topk, order, kwinit);
    k_iou<<<N_PAD, 256, 0, stream>>>(order, nbox, nlabel, sup, diag, rowfut);
    k_scan<<<1, 64, 0, stream>>>(sup, diag, rowfut, kwinit, order, out + 18000);
}